// Round 4
// baseline (879.024 us; speedup 1.0000x reference)
//
#include <hip/hip_runtime.h>
#include <hip/hip_bf16.h>
#include <stdint.h>

#define N_TOK 8192
#define DMODEL 1024
#define HDIM 4096
#define NEXP 8
#define CAP 2048  // k*N/E
#define GATE_BLOCKS (N_TOK / 4)

typedef float floatx4 __attribute__((ext_vector_type(4)));
typedef int int32x4_t __attribute__((ext_vector_type(4)));
typedef int int32x8_t __attribute__((ext_vector_type(8)));

// pack 4 floats -> 4 fp8(e4m3) bytes in one dword
static __device__ __forceinline__ unsigned int pk4_fp8(float a, float b, float c, float d) {
  int r = __builtin_amdgcn_cvt_pk_fp8_f32(a, b, 0, 0);
  r = __builtin_amdgcn_cvt_pk_fp8_f32(c, d, r, 1);
  return (unsigned int)r;
}

// ---------------- gate: logits = x@wg, softmax, top-2, per-block me/ce -------
__global__ __launch_bounds__(256) void gate_kernel(
    const float* __restrict__ x, const float* __restrict__ wg,
    float* __restrict__ topv, int* __restrict__ topi,
    float* __restrict__ me_part, int* __restrict__ ce_part) {
  __shared__ float sm_p[4][NEXP];
  __shared__ int sm_i0[4];
  int wave = threadIdx.x >> 6;
  int lane = threadIdx.x & 63;
  int n = blockIdx.x * 4 + wave;
  float acc[NEXP];
#pragma unroll
  for (int e = 0; e < NEXP; e++) acc[e] = 0.f;
  const float* xr = x + (size_t)n * DMODEL;
#pragma unroll 4
  for (int i = 0; i < DMODEL / 64; i++) {
    int idx = lane + 64 * i;
    float xv = xr[idx];
    const float4* wr = (const float4*)(wg + (size_t)idx * NEXP);
    float4 w0 = wr[0], w1 = wr[1];
    acc[0] += xv * w0.x; acc[1] += xv * w0.y;
    acc[2] += xv * w0.z; acc[3] += xv * w0.w;
    acc[4] += xv * w1.x; acc[5] += xv * w1.y;
    acc[6] += xv * w1.z; acc[7] += xv * w1.w;
  }
#pragma unroll
  for (int e = 0; e < NEXP; e++) {
    float v = acc[e];
#pragma unroll
    for (int off = 32; off > 0; off >>= 1) v += __shfl_down(v, off, 64);
    acc[e] = v;
  }
  if (lane == 0) {
    float mx = acc[0];
#pragma unroll
    for (int e = 1; e < NEXP; e++) mx = fmaxf(mx, acc[e]);
    float p[NEXP]; float s = 0.f;
#pragma unroll
    for (int e = 0; e < NEXP; e++) { p[e] = expf(acc[e] - mx); s += p[e]; }
    float inv = 1.f / s;
#pragma unroll
    for (int e = 0; e < NEXP; e++) p[e] *= inv;
    int i0 = 0; float v0 = p[0];
#pragma unroll
    for (int e = 1; e < NEXP; e++) if (p[e] > v0) { v0 = p[e]; i0 = e; }
    int i1 = -1; float v1 = -1.f;
#pragma unroll
    for (int e = 0; e < NEXP; e++) {
      if (e == i0) continue;
      if (p[e] > v1) { v1 = p[e]; i1 = e; }
    }
    topv[n * 2] = v0; topv[n * 2 + 1] = v1;
    topi[n * 2] = i0; topi[n * 2 + 1] = i1;
#pragma unroll
    for (int e = 0; e < NEXP; e++) sm_p[wave][e] = p[e];
    sm_i0[wave] = i0;
  }
  __syncthreads();
  if (threadIdx.x < NEXP) {
    int e = threadIdx.x;
    float pm = 0.f; int cc = 0;
#pragma unroll
    for (int w = 0; w < 4; w++) {
      pm += sm_p[w][e];
      cc += (sm_i0[w] == e) ? 1 : 0;
    }
    me_part[blockIdx.x * NEXP + e] = pm;
    ce_part[blockIdx.x * NEXP + e] = cc;
  }
}

// ---------------- slot-major positional scan (single block) ------------------
__global__ __launch_bounds__(1024) void scan_kernel(
    const int* __restrict__ topi, const float* __restrict__ topv,
    int* __restrict__ flat_idx, float* __restrict__ cw) {
  __shared__ int hist[16][NEXP];
  __shared__ int base[NEXP];
  int tid = threadIdx.x;
  int w = tid >> 6, lane = tid & 63;
  if (tid < NEXP) base[tid] = 0;
  int vals[16];
#pragma unroll
  for (int c = 0; c < 16; c++) {
    int j = c * 1024 + tid;
    vals[c] = topi[(size_t)(j & 8191) * 2 + (j >> 13)];
  }
  __syncthreads();
  for (int c = 0; c < 16; c++) {
    int j = c * 1024 + tid;
    int slot = j >> 13;
    int n = j & 8191;
    int e = vals[c];
    int rank = 0;
#pragma unroll
    for (int ee = 0; ee < NEXP; ee++) {
      unsigned long long m = __ballot(e == ee);
      if (e == ee) rank = __popcll(m & ((1ull << lane) - 1ull));
      if (lane == ee) hist[w][ee] = __popcll(m);
    }
    __syncthreads();
    if (tid < NEXP) {
      int run = base[tid];
#pragma unroll
      for (int ww = 0; ww < 16; ww++) {
        int t = hist[ww][tid];
        hist[ww][tid] = run;
        run += t;
      }
      base[tid] = run;
    }
    __syncthreads();
    int pos = hist[w][e] + rank;
    bool valid = pos < CAP;
    flat_idx[n * 2 + slot] = e * CAP + (valid ? pos : 0);
    cw[n * 2 + slot] = valid ? topv[n * 2 + slot] : 0.f;
    __syncthreads();
  }
}

// ------- transpose + fp32 -> fp8*512: in [R][C] -> out [C][R] ---------------
// block 256, tile R=128, C=32
__global__ __launch_bounds__(256) void transpose_cvt_fp8(
    const float* __restrict__ in, unsigned char* __restrict__ out,
    int R, int C) {
  __shared__ float tile[32][129];
  const float* inp = in + (size_t)blockIdx.z * R * C;
  unsigned char* outp = out + (size_t)blockIdx.z * R * C;
  int c0 = blockIdx.x * 32, r0 = blockIdx.y * 128;
  int t = threadIdx.x;
#pragma unroll
  for (int p = 0; p < 4; p++) {
    int r = p * 32 + (t >> 3);
    int c4 = (t & 7) * 4;
    float4 v = *(const float4*)(inp + (size_t)(r0 + r) * C + c0 + c4);
    tile[c4 + 0][r] = v.x; tile[c4 + 1][r] = v.y;
    tile[c4 + 2][r] = v.z; tile[c4 + 3][r] = v.w;
  }
  __syncthreads();
  int c = t >> 3, r16 = (t & 7) * 16;
  unsigned int w[4];
#pragma unroll
  for (int j = 0; j < 4; j++) {
    float a = tile[c][r16 + j * 4 + 0] * 512.f;
    float b = tile[c][r16 + j * 4 + 1] * 512.f;
    float cc2 = tile[c][r16 + j * 4 + 2] * 512.f;
    float d = tile[c][r16 + j * 4 + 3] * 512.f;
    w[j] = pk4_fp8(a, b, cc2, d);
  }
  uint4 o; o.x = w[0]; o.y = w[1]; o.z = w[2]; o.w = w[3];
  *(uint4*)(outp + (size_t)(c0 + c) * R + r0 + r16) = o;
}

// ---------------- dispatch scatter: disp[flat] = fp8(x[n]) -------------------
__global__ __launch_bounds__(64) void dispatch_kernel(
    const float* __restrict__ x, const int* __restrict__ flat_idx,
    const float* __restrict__ cw, unsigned char* __restrict__ disp) {
  int a = blockIdx.x;
  if (cw[a] == 0.f) return;
  int n = a >> 1;
  int f = flat_idx[a];
  int lane = threadIdx.x;
  const float4* xr = (const float4*)(x + (size_t)n * DMODEL);
  unsigned int* dr = (unsigned int*)(disp + (size_t)f * DMODEL);
#pragma unroll
  for (int i = 0; i < 4; i++) {
    float4 v = xr[lane + 64 * i];
    dr[lane + 64 * i] = pk4_fp8(v.x, v.y, v.z, v.w);
  }
}

// ------- MX-fp8 MFMA GEMM, LDS-free: operands stream global->VGPR -----------
// A: [E][M][K] fp8 row-major. BT: [E][Ncols][K] fp8. unit MX scales (0x7F).
// grid (Ncols/128, M/128, E), block 256 = 4 waves in 2x2; each wave owns a
// 64x64 output tile and loads its fragments directly (32B/lane contiguous).
// No LDS, no barriers: K-loop is loads<->MFMA with register double-buffer.
template <int K_DIM, bool RELU, bool OUT_FP8>
__global__ __launch_bounds__(256) void gemm_fp8_kernel(
    const unsigned char* __restrict__ A, const unsigned char* __restrict__ BT,
    const float* __restrict__ bias, void* __restrict__ Cout, int M, int Ncols,
    float inv_scale, float out_mult) {
  int e = blockIdx.z;
  int tn = blockIdx.x, tm = blockIdx.y;
  int wv = threadIdx.x >> 6, l = threadIdx.x & 63;
  int wm = wv >> 1, wn = wv & 1;
  int l15 = l & 15, quad = l >> 4;
  // lane's fragment rows: A row (tm*128+wm*64+mi*16+l15), bytes quad*32..+32
  const unsigned char* Ap =
      A + ((size_t)e * M + tm * 128 + wm * 64 + l15) * K_DIM + quad * 32;
  const unsigned char* Bp =
      BT + ((size_t)e * Ncols + tn * 128 + wn * 64 + l15) * K_DIM + quad * 32;
  floatx4 acc[4][4] = {};
  int32x8_t af[4], bf[4], ag[4], bg[4];

#define LOADF(dst, base, idx, k0)                                              \
  {                                                                            \
    const int32x4_t* p =                                                       \
        (const int32x4_t*)((base) + (size_t)(idx)*16 * K_DIM + (k0));          \
    int32x4_t lo = p[0];                                                       \
    int32x4_t hi = p[1];                                                       \
    dst = __builtin_shufflevector(lo, hi, 0, 1, 2, 3, 4, 5, 6, 7);             \
  }

#define LOAD_STAGE(a, b, k0)                                                   \
  {                                                                            \
    _Pragma("unroll") for (int i = 0; i < 4; i++) LOADF(a[i], Ap, i, k0);      \
    _Pragma("unroll") for (int i = 0; i < 4; i++) LOADF(b[i], Bp, i, k0);      \
  }

#define MFMA_STAGE(a, b)                                                       \
  {                                                                            \
    _Pragma("unroll") for (int mi = 0; mi < 4; mi++)                           \
        _Pragma("unroll") for (int ni = 0; ni < 4; ni++) acc[mi][ni] =         \
        __builtin_amdgcn_mfma_scale_f32_16x16x128_f8f6f4(                      \
            a[mi], b[ni], acc[mi][ni], 0, 0, 0, 0x7F7F7F7F, 0, 0x7F7F7F7F);    \
  }

  LOAD_STAGE(af, bf, 0);
#pragma unroll
  for (int k0 = 0; k0 < K_DIM; k0 += 256) {
    LOAD_STAGE(ag, bg, k0 + 128);
    MFMA_STAGE(af, bf);
    if (k0 + 256 < K_DIM) LOAD_STAGE(af, bf, k0 + 256);
    MFMA_STAGE(ag, bg);
  }
#undef LOADF
#undef LOAD_STAGE
#undef MFMA_STAGE

  // epilogue: C/D layout col = lane&15, row = quad*4 + reg
  int row_base = tm * 128 + wm * 64;
  int col_base = tn * 128 + wn * 64;
  const float* be = bias + (size_t)e * Ncols;
#pragma unroll
  for (int ni = 0; ni < 4; ni++) {
    int col = col_base + ni * 16 + l15;
    float bv = be[col];
#pragma unroll
    for (int mi = 0; mi < 4; mi++) {
#pragma unroll
      for (int r = 0; r < 4; r++) {
        int row = row_base + mi * 16 + quad * 4 + r;
        float v = acc[mi][ni][r] * inv_scale + bv;
        if (RELU) v = fmaxf(v, 0.f);
        size_t idx = (size_t)e * M * Ncols + (size_t)row * Ncols + col;
        if (OUT_FP8) {
          float s = fminf(fmaxf(v * out_mult, -440.f), 440.f);
          unsigned int b8 = (unsigned int)__builtin_amdgcn_cvt_pk_fp8_f32(s, s, 0, 0) & 0xFF;
          ((unsigned char*)Cout)[idx] = (unsigned char)b8;
        } else {
          ((float*)Cout)[idx] = v;
        }
      }
    }
  }
}

// ---------------- combine: out[n] = sum_s cw[n,s] * y[flat[n,s]] -------------
__global__ __launch_bounds__(256) void combine_kernel(
    const float* __restrict__ y, const int* __restrict__ flat_idx,
    const float* __restrict__ cw, float* __restrict__ out) {
  int n = blockIdx.x;
  float w0 = cw[n * 2], w1 = cw[n * 2 + 1];
  int f0 = flat_idx[n * 2], f1 = flat_idx[n * 2 + 1];
  const float4* y0 = (const float4*)(y + (size_t)f0 * DMODEL);
  const float4* y1 = (const float4*)(y + (size_t)f1 * DMODEL);
  float4* o = (float4*)(out + (size_t)n * DMODEL);
  int t = threadIdx.x;
  float4 a = y0[t], b = y1[t];
  float4 r;
  r.x = w0 * a.x + w1 * b.x;
  r.y = w0 * a.y + w1 * b.y;
  r.z = w0 * a.z + w1 * b.z;
  r.w = w0 * a.w + w1 * b.w;
  o[t] = r;
}

// ---------------- l_aux = E * sum(me * ce), reducing per-block partials ------
__global__ __launch_bounds__(256) void laux_kernel(
    const float* __restrict__ me_part, const int* __restrict__ ce_part,
    float* __restrict__ out_laux) {
  __shared__ float sme[NEXP][33];
  __shared__ float sce[NEXP][33];
  int tid = threadIdx.x;
  int e = tid >> 5;
  int c = tid & 31;
  float pm = 0.f, cc = 0.f;
  for (int b = c; b < GATE_BLOCKS; b += 32) {
    pm += me_part[b * NEXP + e];
    cc += (float)ce_part[b * NEXP + e];
  }
  sme[e][c] = pm;
  sce[e][c] = cc;
  __syncthreads();
  if (tid < NEXP) {
    float tm = 0.f, tc = 0.f;
#pragma unroll
    for (int i = 0; i < 32; i++) { tm += sme[tid][i]; tc += sce[tid][i]; }
    sme[tid][32] = tm;
    sce[tid][32] = tc;
  }
  __syncthreads();
  if (tid == 0) {
    float s = 0.f;
#pragma unroll
    for (int ee = 0; ee < NEXP; ee++)
      s += (sme[ee][32] / (float)N_TOK) * (sce[ee][32] / (float)N_TOK);
    *out_laux = (float)NEXP * s;
  }
}

extern "C" void kernel_launch(void* const* d_in, const int* in_sizes, int n_in,
                              void* d_out, int out_size, void* d_ws,
                              size_t ws_size, hipStream_t stream) {
  (void)in_sizes; (void)n_in; (void)out_size; (void)ws_size;
  const float* x     = (const float*)d_in[0];
  const float* wg    = (const float*)d_in[1];
  const float* fc1_w = (const float*)d_in[2];
  const float* fc1_b = (const float*)d_in[3];
  const float* fc2_w = (const float*)d_in[4];
  const float* fc2_b = (const float*)d_in[5];
  float* out = (float*)d_out;

  char* ws = (char*)d_ws;
  size_t o = 0;
  unsigned char* fc1t = (unsigned char*)(ws + o); o += (size_t)NEXP * DMODEL * HDIM;  // 32MB
  unsigned char* fc2t = (unsigned char*)(ws + o); o += (size_t)NEXP * DMODEL * HDIM;  // 32MB
  unsigned char* disp = (unsigned char*)(ws + o); o += (size_t)NEXP * CAP * DMODEL;   // 16MB
  unsigned char* hbuf = (unsigned char*)(ws + o); o += (size_t)NEXP * CAP * HDIM;     // 64MB
  float* ybuf = (float*)(ws + o); o += (size_t)NEXP * CAP * DMODEL * 4;               // 64MB
  float* topv = (float*)(ws + o); o += (size_t)N_TOK * 2 * 4;
  int* topi   = (int*)(ws + o);   o += (size_t)N_TOK * 2 * 4;
  int* flat   = (int*)(ws + o);   o += (size_t)N_TOK * 2 * 4;
  float* cw   = (float*)(ws + o); o += (size_t)N_TOK * 2 * 4;
  float* mep  = (float*)(ws + o); o += (size_t)GATE_BLOCKS * NEXP * 4;
  int* cep    = (int*)(ws + o);   o += (size_t)GATE_BLOCKS * NEXP * 4;

  // NOTE: no memset of disp — rows never written are never gathered (cw==0
  // multiplies them out), and fp8-e4m3 garbage is always finite (no inf).

  gate_kernel<<<GATE_BLOCKS, 256, 0, stream>>>(x, wg, topv, topi, mep, cep);
  scan_kernel<<<1, 1024, 0, stream>>>(topi, topv, flat, cw);
  // fc1_w [E][D][H] -> fc1t [E][H][D] fp8*512 ; fc2_w [E][H][D] -> fc2t [E][D][H] fp8*512
  transpose_cvt_fp8<<<dim3(HDIM / 32, DMODEL / 128, NEXP), 256, 0, stream>>>(fc1_w, fc1t, DMODEL, HDIM);
  transpose_cvt_fp8<<<dim3(DMODEL / 32, HDIM / 128, NEXP), 256, 0, stream>>>(fc2_w, fc2t, HDIM, DMODEL);
  dispatch_kernel<<<N_TOK * 2, 64, 0, stream>>>(x, flat, cw, disp);
  // h = relu(disp@fc1^T /512 + b1); stored as fp8 of h*16
  gemm_fp8_kernel<DMODEL, true, true>
      <<<dim3(HDIM / 128, CAP / 128, NEXP), 256, 0, stream>>>(
          disp, fc1t, fc1_b, hbuf, CAP, HDIM, 1.f / 512.f, 16.f);
  // y = (h*16)@(fc2*512)^T /8192 + b2 ; fp32
  gemm_fp8_kernel<HDIM, false, false>
      <<<dim3(DMODEL / 128, CAP / 128, NEXP), 256, 0, stream>>>(
          hbuf, fc2t, fc2_b, ybuf, CAP, DMODEL, 1.f / 8192.f, 1.f);
  combine_kernel<<<N_TOK, 256, 0, stream>>>(ybuf, flat, cw, out);
  laux_kernel<<<1, 256, 0, stream>>>(mep, cep, out + (size_t)N_TOK * DMODEL);
}

// Round 5
// 607.711 us; speedup vs baseline: 1.4465x; 1.4465x over previous
//
#include <hip/hip_runtime.h>
#include <hip/hip_bf16.h>
#include <stdint.h>

#define N_TOK 8192
#define DMODEL 1024
#define HDIM 4096
#define NEXP 8
#define CAP 2048  // k*N/E
#define GATE_BLOCKS (N_TOK / 4)

typedef float floatx4 __attribute__((ext_vector_type(4)));
typedef int int32x4_t __attribute__((ext_vector_type(4)));
typedef int int32x8_t __attribute__((ext_vector_type(8)));

static __device__ __forceinline__ void async_copy16(const void* g, void* l) {
  __builtin_amdgcn_global_load_lds(
      (const __attribute__((address_space(1))) void*)g,
      (__attribute__((address_space(3))) void*)l, 16, 0, 0);
}

// pack 4 floats -> 4 fp8(e4m3) bytes in one dword
static __device__ __forceinline__ unsigned int pk4_fp8(float a, float b, float c, float d) {
  int r = __builtin_amdgcn_cvt_pk_fp8_f32(a, b, 0, 0);
  r = __builtin_amdgcn_cvt_pk_fp8_f32(c, d, r, 1);
  return (unsigned int)r;
}

static __device__ __forceinline__ unsigned short f2bf(float f) {
  union { float f; uint32_t u; } v; v.f = f;
  uint32_t r = (v.u + 0x7FFFu + ((v.u >> 16) & 1u)) >> 16;
  return (unsigned short)r;
}

static __device__ __forceinline__ float bf2f(unsigned short u) {
  union { float f; uint32_t u32; } v; v.u32 = ((uint32_t)u) << 16;
  return v.f;
}

// ---------------- gate: logits = x@wg, softmax, top-2, per-block me/ce -------
__global__ __launch_bounds__(256) void gate_kernel(
    const float* __restrict__ x, const float* __restrict__ wg,
    float* __restrict__ topv, int* __restrict__ topi,
    float* __restrict__ me_part, int* __restrict__ ce_part) {
  __shared__ float sm_p[4][NEXP];
  __shared__ int sm_i0[4];
  int wave = threadIdx.x >> 6;
  int lane = threadIdx.x & 63;
  int n = blockIdx.x * 4 + wave;
  float acc[NEXP];
#pragma unroll
  for (int e = 0; e < NEXP; e++) acc[e] = 0.f;
  const float* xr = x + (size_t)n * DMODEL;
#pragma unroll 4
  for (int i = 0; i < DMODEL / 64; i++) {
    int idx = lane + 64 * i;
    float xv = xr[idx];
    const float4* wr = (const float4*)(wg + (size_t)idx * NEXP);
    float4 w0 = wr[0], w1 = wr[1];
    acc[0] += xv * w0.x; acc[1] += xv * w0.y;
    acc[2] += xv * w0.z; acc[3] += xv * w0.w;
    acc[4] += xv * w1.x; acc[5] += xv * w1.y;
    acc[6] += xv * w1.z; acc[7] += xv * w1.w;
  }
#pragma unroll
  for (int e = 0; e < NEXP; e++) {
    float v = acc[e];
#pragma unroll
    for (int off = 32; off > 0; off >>= 1) v += __shfl_down(v, off, 64);
    acc[e] = v;
  }
  if (lane == 0) {
    float mx = acc[0];
#pragma unroll
    for (int e = 1; e < NEXP; e++) mx = fmaxf(mx, acc[e]);
    float p[NEXP]; float s = 0.f;
#pragma unroll
    for (int e = 0; e < NEXP; e++) { p[e] = expf(acc[e] - mx); s += p[e]; }
    float inv = 1.f / s;
#pragma unroll
    for (int e = 0; e < NEXP; e++) p[e] *= inv;
    int i0 = 0; float v0 = p[0];
#pragma unroll
    for (int e = 1; e < NEXP; e++) if (p[e] > v0) { v0 = p[e]; i0 = e; }
    int i1 = -1; float v1 = -1.f;
#pragma unroll
    for (int e = 0; e < NEXP; e++) {
      if (e == i0) continue;
      if (p[e] > v1) { v1 = p[e]; i1 = e; }
    }
    topv[n * 2] = v0; topv[n * 2 + 1] = v1;
    topi[n * 2] = i0; topi[n * 2 + 1] = i1;
#pragma unroll
    for (int e = 0; e < NEXP; e++) sm_p[wave][e] = p[e];
    sm_i0[wave] = i0;
  }
  __syncthreads();
  if (threadIdx.x < NEXP) {
    int e = threadIdx.x;
    float pm = 0.f; int cc = 0;
#pragma unroll
    for (int w = 0; w < 4; w++) {
      pm += sm_p[w][e];
      cc += (sm_i0[w] == e) ? 1 : 0;
    }
    me_part[blockIdx.x * NEXP + e] = pm;
    ce_part[blockIdx.x * NEXP + e] = cc;
  }
}

// ---------------- slot-major positional scan (single block) ------------------
__global__ __launch_bounds__(1024) void scan_kernel(
    const int* __restrict__ topi, const float* __restrict__ topv,
    int* __restrict__ flat_idx, float* __restrict__ cw) {
  __shared__ int hist[16][NEXP];
  __shared__ int base[NEXP];
  int tid = threadIdx.x;
  int w = tid >> 6, lane = tid & 63;
  if (tid < NEXP) base[tid] = 0;
  int vals[16];
#pragma unroll
  for (int c = 0; c < 16; c++) {
    int j = c * 1024 + tid;
    vals[c] = topi[(size_t)(j & 8191) * 2 + (j >> 13)];
  }
  __syncthreads();
  for (int c = 0; c < 16; c++) {
    int j = c * 1024 + tid;
    int slot = j >> 13;
    int n = j & 8191;
    int e = vals[c];
    int rank = 0;
#pragma unroll
    for (int ee = 0; ee < NEXP; ee++) {
      unsigned long long m = __ballot(e == ee);
      if (e == ee) rank = __popcll(m & ((1ull << lane) - 1ull));
      if (lane == ee) hist[w][ee] = __popcll(m);
    }
    __syncthreads();
    if (tid < NEXP) {
      int run = base[tid];
#pragma unroll
      for (int ww = 0; ww < 16; ww++) {
        int t = hist[ww][tid];
        hist[ww][tid] = run;
        run += t;
      }
      base[tid] = run;
    }
    __syncthreads();
    int pos = hist[w][e] + rank;
    bool valid = pos < CAP;
    flat_idx[n * 2 + slot] = e * CAP + (valid ? pos : 0);
    cw[n * 2 + slot] = valid ? topv[n * 2 + slot] : 0.f;
    __syncthreads();
  }
}

// ------- transpose + fp32 -> fp8*512: in [R][C] -> out [C][R] ---------------
// block 256, tile R=128, C=32
__global__ __launch_bounds__(256) void transpose_cvt_fp8(
    const float* __restrict__ in, unsigned char* __restrict__ out,
    int R, int C) {
  __shared__ float tile[32][129];
  const float* inp = in + (size_t)blockIdx.z * R * C;
  unsigned char* outp = out + (size_t)blockIdx.z * R * C;
  int c0 = blockIdx.x * 32, r0 = blockIdx.y * 128;
  int t = threadIdx.x;
#pragma unroll
  for (int p = 0; p < 4; p++) {
    int r = p * 32 + (t >> 3);
    int c4 = (t & 7) * 4;
    float4 v = *(const float4*)(inp + (size_t)(r0 + r) * C + c0 + c4);
    tile[c4 + 0][r] = v.x; tile[c4 + 1][r] = v.y;
    tile[c4 + 2][r] = v.z; tile[c4 + 3][r] = v.w;
  }
  __syncthreads();
  int c = t >> 3, r16 = (t & 7) * 16;
  unsigned int w[4];
#pragma unroll
  for (int j = 0; j < 4; j++) {
    float a = tile[c][r16 + j * 4 + 0] * 512.f;
    float b = tile[c][r16 + j * 4 + 1] * 512.f;
    float cc2 = tile[c][r16 + j * 4 + 2] * 512.f;
    float d = tile[c][r16 + j * 4 + 3] * 512.f;
    w[j] = pk4_fp8(a, b, cc2, d);
  }
  uint4 o; o.x = w[0]; o.y = w[1]; o.z = w[2]; o.w = w[3];
  *(uint4*)(outp + (size_t)(c0 + c) * R + r0 + r16) = o;
}

// ---------------- dispatch scatter: disp[flat] = fp8(x[n]) -------------------
__global__ __launch_bounds__(64) void dispatch_kernel(
    const float* __restrict__ x, const int* __restrict__ flat_idx,
    const float* __restrict__ cw, unsigned char* __restrict__ disp) {
  int a = blockIdx.x;
  if (cw[a] == 0.f) return;
  int n = a >> 1;
  int f = flat_idx[a];
  int lane = threadIdx.x;
  const float4* xr = (const float4*)(x + (size_t)n * DMODEL);
  unsigned int* dr = (unsigned int*)(disp + (size_t)f * DMODEL);
#pragma unroll
  for (int i = 0; i < 4; i++) {
    float4 v = xr[lane + 64 * i];
    dr[lane + 64 * i] = pk4_fp8(v.x, v.y, v.z, v.w);
  }
}

// ------- MX-fp8 MFMA GEMM: C[e] = act(A[e] @ B[e]^T * inv_scale + bias) -----
// A: [E][M][K] fp8 row-major. BT: [E][Ncols][K] fp8. unit MX scales (0x7F).
// grid (Ncols/128, M/128, E), block 256 (4 waves, 2x2 of 64x64 per wave).
// K-loop order: [sync(drain k); ds_read frags; sync; issue loads k+1; MFMA k]
// so the global->LDS latency of stage k+1 overlaps stage k's MFMA block.
// OUT_MODE: 0 = fp32, 1 = fp8 (scaled by out_mult), 2 = bf16
template <int K_DIM, bool RELU, int OUT_MODE>
__global__ __launch_bounds__(256) void gemm_fp8_kernel(
    const unsigned char* __restrict__ A, const unsigned char* __restrict__ BT,
    const float* __restrict__ bias, void* __restrict__ Cout, int M, int Ncols,
    float inv_scale, float out_mult) {
  constexpr int BK = 128;
  constexpr int NSTAGE = K_DIM / BK;
  __shared__ unsigned char As[128 * BK];  // 16KB, xor-swizzled 16B chunks
  __shared__ unsigned char Bs[128 * BK];
  int e = blockIdx.z;
  int tn = blockIdx.x, tm = blockIdx.y;
  const unsigned char* Ae = A + (size_t)e * M * K_DIM + (size_t)tm * 128 * K_DIM;
  const unsigned char* Be = BT + (size_t)e * Ncols * K_DIM + (size_t)tn * 128 * K_DIM;
  int wv = threadIdx.x >> 6, l = threadIdx.x & 63;
  int wm = wv >> 1, wn = wv & 1;
  int l15 = l & 15, quad = l >> 4;
  // staging: lane covers LDS chunk (i*256 + wv*64 + l); row r=chunk>>3, slot=l&7
  int rbase = wv * 8 + (l >> 3);
  int cg = (l & 7) ^ ((l >> 3) & 7);  // xor swizzle: slot s of row r holds chunk s^(r&7)
  floatx4 acc[4][4] = {};

#define STAGE_LOADS(k0)                                                        \
  {                                                                            \
    _Pragma("unroll") for (int i = 0; i < 4; i++) {                            \
      int r = rbase + i * 32;                                                  \
      async_copy16(Ae + (size_t)r * K_DIM + (k0) + cg * 16,                    \
                   As + i * 4096 + wv * 1024);                                 \
      async_copy16(Be + (size_t)r * K_DIM + (k0) + cg * 16,                    \
                   Bs + i * 4096 + wv * 1024);                                 \
    }                                                                          \
  }

  STAGE_LOADS(0);
#pragma unroll
  for (int s = 0; s < NSTAGE; s++) {
    __syncthreads();  // drain stage-s loads; LDS tiles ready
    int32x8_t af[4], bf[4];
#pragma unroll
    for (int mi = 0; mi < 4; mi++) {
      int m = wm * 64 + mi * 16 + l15;
      int x0 = (quad * 2) ^ (m & 7), x1 = (quad * 2 + 1) ^ (m & 7);
      int32x4_t lo = *(const int32x4_t*)(As + m * 128 + x0 * 16);
      int32x4_t hi = *(const int32x4_t*)(As + m * 128 + x1 * 16);
      af[mi] = __builtin_shufflevector(lo, hi, 0, 1, 2, 3, 4, 5, 6, 7);
    }
#pragma unroll
    for (int ni = 0; ni < 4; ni++) {
      int m = wn * 64 + ni * 16 + l15;
      int x0 = (quad * 2) ^ (m & 7), x1 = (quad * 2 + 1) ^ (m & 7);
      int32x4_t lo = *(const int32x4_t*)(Bs + m * 128 + x0 * 16);
      int32x4_t hi = *(const int32x4_t*)(Bs + m * 128 + x1 * 16);
      bf[ni] = __builtin_shufflevector(lo, hi, 0, 1, 2, 3, 4, 5, 6, 7);
    }
    __syncthreads();  // all waves done reading LDS
    if (s + 1 < NSTAGE) STAGE_LOADS((s + 1) * BK);  // overlaps MFMAs below
#pragma unroll
    for (int mi = 0; mi < 4; mi++)
#pragma unroll
      for (int ni = 0; ni < 4; ni++)
        acc[mi][ni] = __builtin_amdgcn_mfma_scale_f32_16x16x128_f8f6f4(
            af[mi], bf[ni], acc[mi][ni], 0, 0, 0, 0x7F7F7F7F, 0, 0x7F7F7F7F);
  }
#undef STAGE_LOADS

  // epilogue: C/D layout col = lane&15, row = quad*4 + reg
  int row_base = tm * 128 + wm * 64;
  int col_base = tn * 128 + wn * 64;
  const float* be = bias + (size_t)e * Ncols;
#pragma unroll
  for (int ni = 0; ni < 4; ni++) {
    int col = col_base + ni * 16 + l15;
    float bv = be[col];
#pragma unroll
    for (int mi = 0; mi < 4; mi++) {
#pragma unroll
      for (int r = 0; r < 4; r++) {
        int row = row_base + mi * 16 + quad * 4 + r;
        float v = acc[mi][ni][r] * inv_scale + bv;
        if (RELU) v = fmaxf(v, 0.f);
        size_t idx = (size_t)e * M * Ncols + (size_t)row * Ncols + col;
        if (OUT_MODE == 1) {
          float s = fminf(fmaxf(v * out_mult, -440.f), 440.f);
          unsigned int b8 = (unsigned int)__builtin_amdgcn_cvt_pk_fp8_f32(s, s, 0, 0) & 0xFF;
          ((unsigned char*)Cout)[idx] = (unsigned char)b8;
        } else if (OUT_MODE == 2) {
          ((unsigned short*)Cout)[idx] = f2bf(v);
        } else {
          ((float*)Cout)[idx] = v;
        }
      }
    }
  }
}

// ------- combine: out[n] = sum_s cw[n,s] * y[flat[n,s]], y in bf16 ----------
__global__ __launch_bounds__(256) void combine_kernel(
    const unsigned short* __restrict__ y, const int* __restrict__ flat_idx,
    const float* __restrict__ cw, float* __restrict__ out) {
  int n = blockIdx.x;
  float w0 = cw[n * 2], w1 = cw[n * 2 + 1];
  int f0 = flat_idx[n * 2], f1 = flat_idx[n * 2 + 1];
  const ushort2* y0 = (const ushort2*)(y + (size_t)f0 * DMODEL);
  const ushort2* y1 = (const ushort2*)(y + (size_t)f1 * DMODEL);
  float2* o = (float2*)(out + (size_t)n * DMODEL);
  int t = threadIdx.x;  // 256 threads x 2 elems x 2 iters = 1024
#pragma unroll
  for (int i = 0; i < 2; i++) {
    int j = t + i * 256;
    ushort2 a = y0[j], b = y1[j];
    float2 r;
    r.x = w0 * bf2f(a.x) + w1 * bf2f(b.x);
    r.y = w0 * bf2f(a.y) + w1 * bf2f(b.y);
    o[j] = r;
  }
}

// ---------------- l_aux = E * sum(me * ce), reducing per-block partials ------
__global__ __launch_bounds__(256) void laux_kernel(
    const float* __restrict__ me_part, const int* __restrict__ ce_part,
    float* __restrict__ out_laux) {
  __shared__ float sme[NEXP][33];
  __shared__ float sce[NEXP][33];
  int tid = threadIdx.x;
  int e = tid >> 5;
  int c = tid & 31;
  float pm = 0.f, cc = 0.f;
  for (int b = c; b < GATE_BLOCKS; b += 32) {
    pm += me_part[b * NEXP + e];
    cc += (float)ce_part[b * NEXP + e];
  }
  sme[e][c] = pm;
  sce[e][c] = cc;
  __syncthreads();
  if (tid < NEXP) {
    float tm = 0.f, tc = 0.f;
#pragma unroll
    for (int i = 0; i < 32; i++) { tm += sme[tid][i]; tc += sce[tid][i]; }
    sme[tid][32] = tm;
    sce[tid][32] = tc;
  }
  __syncthreads();
  if (tid == 0) {
    float s = 0.f;
#pragma unroll
    for (int ee = 0; ee < NEXP; ee++)
      s += (sme[ee][32] / (float)N_TOK) * (sce[ee][32] / (float)N_TOK);
    *out_laux = (float)NEXP * s;
  }
}

extern "C" void kernel_launch(void* const* d_in, const int* in_sizes, int n_in,
                              void* d_out, int out_size, void* d_ws,
                              size_t ws_size, hipStream_t stream) {
  (void)in_sizes; (void)n_in; (void)out_size; (void)ws_size;
  const float* x     = (const float*)d_in[0];
  const float* wg    = (const float*)d_in[1];
  const float* fc1_w = (const float*)d_in[2];
  const float* fc1_b = (const float*)d_in[3];
  const float* fc2_w = (const float*)d_in[4];
  const float* fc2_b = (const float*)d_in[5];
  float* out = (float*)d_out;

  char* ws = (char*)d_ws;
  size_t o = 0;
  unsigned char* fc1t = (unsigned char*)(ws + o); o += (size_t)NEXP * DMODEL * HDIM;  // 32MB
  unsigned char* fc2t = (unsigned char*)(ws + o); o += (size_t)NEXP * DMODEL * HDIM;  // 32MB
  unsigned char* disp = (unsigned char*)(ws + o); o += (size_t)NEXP * CAP * DMODEL;   // 16MB
  unsigned char* hbuf = (unsigned char*)(ws + o); o += (size_t)NEXP * CAP * HDIM;     // 64MB
  unsigned short* ybuf = (unsigned short*)(ws + o); o += (size_t)NEXP * CAP * DMODEL * 2;  // 32MB bf16
  float* topv = (float*)(ws + o); o += (size_t)N_TOK * 2 * 4;
  int* topi   = (int*)(ws + o);   o += (size_t)N_TOK * 2 * 4;
  int* flat   = (int*)(ws + o);   o += (size_t)N_TOK * 2 * 4;
  float* cw   = (float*)(ws + o); o += (size_t)N_TOK * 2 * 4;
  float* mep  = (float*)(ws + o); o += (size_t)GATE_BLOCKS * NEXP * 4;
  int* cep    = (int*)(ws + o);   o += (size_t)GATE_BLOCKS * NEXP * 4;

  // no memset of disp: unwritten capacity rows are never gathered (cw==0),
  // and fp8-e4m3 bit patterns are always finite.

  gate_kernel<<<GATE_BLOCKS, 256, 0, stream>>>(x, wg, topv, topi, mep, cep);
  scan_kernel<<<1, 1024, 0, stream>>>(topi, topv, flat, cw);
  // fc1_w [E][D][H] -> fc1t [E][H][D] fp8*512 ; fc2_w [E][H][D] -> fc2t [E][D][H] fp8*512
  transpose_cvt_fp8<<<dim3(HDIM / 32, DMODEL / 128, NEXP), 256, 0, stream>>>(fc1_w, fc1t, DMODEL, HDIM);
  transpose_cvt_fp8<<<dim3(DMODEL / 32, HDIM / 128, NEXP), 256, 0, stream>>>(fc2_w, fc2t, HDIM, DMODEL);
  dispatch_kernel<<<N_TOK * 2, 64, 0, stream>>>(x, flat, cw, disp);
  // h = relu(disp@fc1^T /512 + b1); stored as fp8 of h*16
  gemm_fp8_kernel<DMODEL, true, 1>
      <<<dim3(HDIM / 128, CAP / 128, NEXP), 256, 0, stream>>>(
          disp, fc1t, fc1_b, hbuf, CAP, HDIM, 1.f / 512.f, 16.f);
  // y = (h*16)@(fc2*512)^T /8192 + b2 ; bf16
  gemm_fp8_kernel<HDIM, false, 2>
      <<<dim3(DMODEL / 128, CAP / 128, NEXP), 256, 0, stream>>>(
          hbuf, fc2t, fc2_b, ybuf, CAP, DMODEL, 1.f / 8192.f, 1.f);
  combine_kernel<<<N_TOK, 256, 0, stream>>>(ybuf, flat, cw, out);
  laux_kernel<<<1, 256, 0, stream>>>(mep, cep, out + (size_t)N_TOK * DMODEL);
}